// Round 6
// baseline (162.261 us; speedup 1.0000x reference)
//
#include <hip/hip_runtime.h>
#include <hip/hip_bf16.h>
#include <stdint.h>

constexpr int NN = 1024;   // nodes
constexpr int DD = 128;    // NODE_DIM == HID
constexpr int EDIM = 32;   // EDGE_DIM
constexpr int NR = 16;     // NREL

using short4v = __attribute__((ext_vector_type(4))) short;
using short8v = __attribute__((ext_vector_type(8))) short;
using f32x4   = __attribute__((ext_vector_type(4))) float;

__device__ __forceinline__ short f2bf(float x) {
  __hip_bfloat16 h = __float2bfloat16(x);   // RNE
  return __builtin_bit_cast(short, h);
}

// async global->LDS, 16B per lane. LDS dest = uniform base + lane*16 (m104);
// global src is per-lane. Low 32 bits of a generic LDS pointer are the offset.
__device__ __forceinline__ void gl_lds16(const void* g, void* l) {
  __builtin_amdgcn_global_load_lds(
      (const __attribute__((address_space(1))) unsigned int*)(uintptr_t)g,
      (__attribute__((address_space(3))) unsigned int*)(uint32_t)(uintptr_t)l,
      16, 0, 0);
}

// ---------------- K1: rsinv[i] = 1/(rowsum(adj[i]) + 1e-6) ----------------
__global__ __launch_bounds__(256) void k_rowsum(const float* __restrict__ adj,
                                                float* __restrict__ rsinv) {
  int i = blockIdx.x, t = threadIdx.x;
  const float4* row = (const float4*)(adj + (size_t)i * NN);
  float4 v = row[t];
  float s = v.x + v.y + v.z + v.w;
  #pragma unroll
  for (int off = 32; off > 0; off >>= 1) s += __shfl_down(s, off, 64);
  __shared__ float red[4];
  if ((t & 63) == 0) red[t >> 6] = s;
  __syncthreads();
  if (t == 0) rsinv[i] = 1.0f / (red[0] + red[1] + red[2] + red[3] + 1e-6f);
}

// ---------------- K2a: partial[kc][i][h] ----------------
__global__ __launch_bounds__(256) void k_adjgemm(const float* __restrict__ adj,
                                                 const float* __restrict__ X,
                                                 float* __restrict__ part) {
  __shared__ float sadj[16][128];
  int t = threadIdx.x;
  int ic = blockIdx.x & 63, kc = blockIdx.x >> 6;
  int i0 = ic * 16, k0 = kc * 128;
  {
    int il = t >> 4;
    int kl = (t & 15) * 8;
    const float4* src = (const float4*)(adj + (size_t)(i0 + il) * NN + k0 + kl);
    *(float4*)&sadj[il][kl]     = src[0];
    *(float4*)&sadj[il][kl + 4] = src[1];
  }
  __syncthreads();
  int h = t & 127, ii = t >> 7;
  float acc[8] = {0,0,0,0,0,0,0,0};
  for (int k = 0; k < 128; k += 4) {
    float x0 = X[(size_t)(k0 + k) * DD + h];
    float x1 = X[(size_t)(k0 + k + 1) * DD + h];
    float x2 = X[(size_t)(k0 + k + 2) * DD + h];
    float x3 = X[(size_t)(k0 + k + 3) * DD + h];
    #pragma unroll
    for (int m = 0; m < 8; ++m) {
      int il = ii + m * 2;
      float4 a = *(const float4*)&sadj[il][k];
      acc[m] += a.x * x0 + a.y * x1 + a.z * x2 + a.w * x3;
    }
  }
  #pragma unroll
  for (int m = 0; m < 8; ++m)
    part[((size_t)kc * NN + (i0 + ii + m * 2)) * DD + h] = acc[m];
}

// ---------------- K3/K5 (fused aggfin+dense) ----------------
__global__ __launch_bounds__(256) void k_dense2f(const float* __restrict__ X,
                                                 const float* __restrict__ part,
                                                 const float* __restrict__ rsinv,
                                                 const float* __restrict__ W,
                                                 const float* __restrict__ b,
                                                 float* __restrict__ out) {
  __shared__ float sagg[2][128];
  int t = threadIdx.x;
  int ig = t >> 7, h = t & 127;
  int i = blockIdx.x * 2 + ig;
  {
    float s = 0.f;
    #pragma unroll
    for (int kc = 0; kc < 8; ++kc) s += part[(size_t)kc * NN * DD + (size_t)i * DD + h];
    sagg[ig][h] = s * rsinv[i];
  }
  __syncthreads();
  const float4* xr = (const float4*)(X + (size_t)i * DD);
  const float4* ar = (const float4*)(&sagg[ig][0]);
  const float4* w1 = (const float4*)(W + (size_t)h * 256);
  const float4* w2 = (const float4*)(W + (size_t)h * 256 + DD);
  float acc = b[h];
  #pragma unroll 8
  for (int k = 0; k < 32; ++k) {
    float4 x = xr[k], w = w1[k];
    acc += x.x * w.x + x.y * w.y + x.z * w.z + x.w * w.w;
  }
  #pragma unroll 8
  for (int k = 0; k < 32; ++k) {
    float4 y = ar[k], w = w2[k];
    acc += y.x * w.x + y.y * w.y + y.z * w.z + y.w * w.w;
  }
  out[(size_t)i * DD + h] = fmaxf(acc, 0.f);
}

// ---------------- K6: Aib/Bmat precompute ----------------
__global__ __launch_bounds__(256) void k_ab(const float* __restrict__ h2,
                                            const float* __restrict__ Wc1,
                                            const float* __restrict__ bc1,
                                            float* __restrict__ Aib,
                                            float* __restrict__ Bmat) {
  int t = threadIdx.x;
  int i = blockIdx.x * 2 + (t >> 7), h = t & 127;
  const float4* xr = (const float4*)(h2 + (size_t)i * DD);
  const float4* wa = (const float4*)(Wc1 + (size_t)h * 288);
  const float4* wb = (const float4*)(Wc1 + (size_t)h * 288 + 128);
  float aa = bc1[h], bb = 0.f;
  #pragma unroll 8
  for (int k = 0; k < 32; ++k) {
    float4 x = xr[k];
    float4 a = wa[k], b2 = wb[k];
    aa += x.x * a.x + x.y * a.y + x.z * a.z + x.w * a.w;
    bb += x.x * b2.x + x.y * b2.y + x.z * b2.z + x.w * b2.w;
  }
  Aib[(size_t)i * DD + h] = aa;
  Bmat[(size_t)i * DD + h] = bb;
}

// ---------------- K7: fused edge stage (v6: 4 waves/SIMD, ci half-0 hoisted) ----
// Block: 16 i (ig) x 64 j (jg); wave w: j = jg*64 + w*16 + c, bodies t=0..15 -> i0+t.
// VMEM issue order pinned per body by memory-clobber fences:
//   [ci half-0 (LDS, pre-wait)] [wait vmcnt(N)] [ds_read edge] |f| [glds x2] |f| [rest]
// Ledger (exact): stores 1/body, glds 2/body -> body0 vmcnt(2), body1 vmcnt(3),
// steady vmcnt(4). Source-side XOR swizzle: LDS[X] = tile[X ^ (((X>>7)&7)<<4)].
// __launch_bounds__(256,4): LDS 40960 = 160KB/4 exactly -> 4 blocks/CU, zero tail
// at 1024 blocks, iff regs fit 128 (unified VGPR+AGPR).

#define EDGE_BODY(T, SLOT, VMN) do {                                          \
    const float* ap_ = aibs + (T) * 128 + 4 * g;                              \
    f32x4 ci0_[4];                                                            \
    _Pragma("unroll")                                                         \
    for (int n = 0; n < 4; ++n) {                                             \
      float4 av_ = *(const float4*)(ap_ + 16 * n);                            \
      ci0_[n][0] = av_.x + bjv[n].x; ci0_[n][1] = av_.y + bjv[n].y;           \
      ci0_[n][2] = av_.z + bjv[n].z; ci0_[n][3] = av_.w + bjv[n].w;           \
    }                                                                         \
    asm volatile("s_waitcnt vmcnt(" #VMN ")" ::: "memory");                   \
    char* ebuf_ = (SLOT) ? esw1 : esw0;                                       \
    float4 e0_ = *(const float4*)(ebuf_ + rd0);                               \
    float4 e1_ = *(const float4*)(ebuf_ + rd1);                               \
    asm volatile("" ::: "memory");  /* pin ds_read(edge) before glds */       \
    { int tpf_ = (T) + 2 > 15 ? 15 : (T) + 2;                                 \
      const char* src_ = ebl + (size_t)tpf_ * 131072;                         \
      gl_lds16(src_, ebuf_);                                                  \
      gl_lds16(src_ + 1024, ebuf_ + 1024); }                                  \
    asm volatile("" ::: "memory");  /* pin glds before P-tile ds ops/store */ \
    short8v ef_;                                                              \
    ef_[0]=f2bf(e0_.x); ef_[1]=f2bf(e0_.y); ef_[2]=f2bf(e0_.z); ef_[3]=f2bf(e0_.w); \
    ef_[4]=f2bf(e1_.x); ef_[5]=f2bf(e1_.y); ef_[6]=f2bf(e1_.z); ef_[7]=f2bf(e1_.w); \
    int i_ = i0 + (T);                                                        \
    _Pragma("unroll")                                                         \
    for (int n = 0; n < 4; ++n) {                                             \
      f32x4 acc_ = __builtin_amdgcn_mfma_f32_16x16x32_bf16(weF[n], ef_, ci0_[n], 0, 0, 0); \
      short4v pk_;                                                            \
      pk_[0] = f2bf(fmaxf(acc_[0], 0.f)); pk_[1] = f2bf(fmaxf(acc_[1], 0.f)); \
      pk_[2] = f2bf(fmaxf(acc_[2], 0.f)); pk_[3] = f2bf(fmaxf(acc_[3], 0.f)); \
      *(short4v*)(psm + (((n >> 1) << 10) + ((n & 1) << 9) + wroff)) = pk_;   \
    }                                                                         \
    _Pragma("unroll")                                                         \
    for (int n = 4; n < 8; ++n) {                                             \
      float4 av_ = *(const float4*)(ap_ + 16 * n);                            \
      f32x4 ci_;                                                              \
      ci_[0] = av_.x + bjv[n].x; ci_[1] = av_.y + bjv[n].y;                   \
      ci_[2] = av_.z + bjv[n].z; ci_[3] = av_.w + bjv[n].w;                   \
      f32x4 acc_ = __builtin_amdgcn_mfma_f32_16x16x32_bf16(weF[n], ef_, ci_, 0, 0, 0); \
      short4v pk_;                                                            \
      pk_[0] = f2bf(fmaxf(acc_[0], 0.f)); pk_[1] = f2bf(fmaxf(acc_[1], 0.f)); \
      pk_[2] = f2bf(fmaxf(acc_[2], 0.f)); pk_[3] = f2bf(fmaxf(acc_[3], 0.f)); \
      *(short4v*)(psm + (((n >> 1) << 10) + ((n & 1) << 9) + wroff)) = pk_;   \
    }                                                                         \
    f32x4 acc2_;                                                              \
    acc2_[0] = bc2v.x; acc2_[1] = bc2v.y; acc2_[2] = bc2v.z; acc2_[3] = bc2v.w; \
    _Pragma("unroll")                                                         \
    for (int kk = 0; kk < 4; ++kk) {                                          \
      short8v pb_ = *(short8v*)(psm + ((kk << 10) + rdP));                    \
      acc2_ = __builtin_amdgcn_mfma_f32_16x16x32_bf16(wcF[kk], pb_, acc2_, 0, 0, 0); \
    }                                                                         \
    bool diag_ = (j == i_);                                                   \
    float4 o_;                                                                \
    o_.x = diag_ ? 0.f : acc2_[0];                                            \
    o_.y = diag_ ? 0.f : acc2_[1];                                            \
    o_.z = diag_ ? 0.f : acc2_[2];                                            \
    o_.w = diag_ ? 0.f : acc2_[3];                                            \
    *(float4*)(out + ((size_t)i_ * NN + j) * NR + 4 * g) = o_;                \
  } while (0)

__global__ __launch_bounds__(256, 4) void k_edge(const float* __restrict__ edge,
                                                 const float* __restrict__ Wc1,
                                                 const float* __restrict__ Wc2,
                                                 const float* __restrict__ bc2,
                                                 const float* __restrict__ Aib,
                                                 const float* __restrict__ Bmat,
                                                 float* __restrict__ out) {
  __shared__ __align__(16) char esm[4][2][2048];    // 16 KB edge ring (per wave x 2 slots)
  __shared__ __align__(16) char psm_all[4][4096];   // 16 KB P tiles
  __shared__ __align__(16) float aibs[16 * 128];    // 8 KB Aib panel    -> 40960 total
  int tid = threadIdx.x;
  int w = tid >> 6, lane = tid & 63;
  int c = lane & 15, g = lane >> 4;
  int ig = blockIdx.x >> 4, jg = blockIdx.x & 15;
  int i0 = ig * 16;
  int j0w = jg * 64 + w * 16;
  int j = j0w + c;

  // stage Aib panel (16 i x 128 h) into LDS; only barrier in the kernel
  {
    int ii = tid >> 4, h8 = (tid & 15) * 8;
    const float4* s = (const float4*)(Aib + (size_t)(i0 + ii) * DD + h8);
    *(float4*)(aibs + ii * 128 + h8)     = s[0];
    *(float4*)(aibs + ii * 128 + h8 + 4) = s[1];
  }
  __syncthreads();

  // We fragments: A1[m=c][k=8g+jj] = Wc1[16n+c][256+8g+jj]
  short8v weF[8];
  #pragma unroll
  for (int n = 0; n < 8; ++n) {
    const float* p = Wc1 + (size_t)(16 * n + c) * 288 + 256 + 8 * g;
    float4 f0 = *(const float4*)p;
    float4 f1 = *(const float4*)(p + 4);
    short8v s;
    s[0]=f2bf(f0.x); s[1]=f2bf(f0.y); s[2]=f2bf(f0.z); s[3]=f2bf(f0.w);
    s[4]=f2bf(f1.x); s[5]=f2bf(f1.y); s[6]=f2bf(f1.z); s[7]=f2bf(f1.w);
    weF[n] = s;
  }
  // Wc2 fragments: A2[m=c][k=32kk+8g+jj]
  short8v wcF[4];
  #pragma unroll
  for (int kk = 0; kk < 4; ++kk) {
    const float* p = Wc2 + (size_t)c * DD + 32 * kk + 8 * g;
    float4 f0 = *(const float4*)p;
    float4 f1 = *(const float4*)(p + 4);
    short8v s;
    s[0]=f2bf(f0.x); s[1]=f2bf(f0.y); s[2]=f2bf(f0.z); s[3]=f2bf(f0.w);
    s[4]=f2bf(f1.x); s[5]=f2bf(f1.y); s[6]=f2bf(f1.z); s[7]=f2bf(f1.w);
    wcF[kk] = s;
  }
  float4 bc2v = *(const float4*)(bc2 + 4 * g);
  // Bmat for this lane's j, reused across all 16 i's
  float4 bjv[8];
  #pragma unroll
  for (int n = 0; n < 8; ++n)
    bjv[n] = *(const float4*)(Bmat + (size_t)j * DD + 16 * n + 4 * g);

  char* esw0 = &esm[w][0][0];
  char* esw1 = &esm[w][1][0];
  char* psm  = &psm_all[w][0];
  // per-lane swizzled source offset within a tile (involution on bits 4-6)
  const char* ebl = (const char*)edge + ((size_t)i0 * NN + j0w) * (EDIM * 4)
                    + ((lane * 16) ^ (((lane >> 3) & 7) << 4));
  // LDS read addrs for this lane's edge slice (same involution)
  int rd0 = c * 128 + ((g * 32)      ^ ((c & 7) << 4));
  int rd1 = c * 128 + ((g * 32 + 16) ^ ((c & 7) << 4));
  // P-tile write/read offsets (derived conflict-free transpose layout)
  int wroff = (c << 4) + ((g & 1) << 3) + ((g >> 1) << 8);
  int rdP   = (g << 8) + (c << 4);

  // prologue: stage tiles 0 and 1 (ordered against later ops by the wait asm)
  gl_lds16(ebl,                  esw0);
  gl_lds16(ebl + 1024,           esw0 + 1024);
  gl_lds16(ebl + 131072,         esw1);
  gl_lds16(ebl + 131072 + 1024,  esw1 + 1024);

  EDGE_BODY(0, 0, 2);
  EDGE_BODY(1, 1, 3);
  #pragma unroll 1
  for (int t = 2; t < 16; t += 2) {
    EDGE_BODY(t,     0, 4);
    EDGE_BODY(t + 1, 1, 4);
  }
}

extern "C" void kernel_launch(void* const* d_in, const int* in_sizes, int n_in,
                              void* d_out, int out_size, void* d_ws, size_t ws_size,
                              hipStream_t stream) {
  const float* node_feat = (const float*)d_in[0];
  const float* edge_feat = (const float*)d_in[1];
  const float* adj  = (const float*)d_in[2];
  const float* W_g1 = (const float*)d_in[3];
  const float* b_g1 = (const float*)d_in[4];
  const float* W_g2 = (const float*)d_in[5];
  const float* b_g2 = (const float*)d_in[6];
  const float* W_c1 = (const float*)d_in[7];
  const float* b_c1 = (const float*)d_in[8];
  const float* W_c2 = (const float*)d_in[9];
  const float* b_c2 = (const float*)d_in[10];
  float* out = (float*)d_out;

  float* ws    = (float*)d_ws;
  float* rsinv = ws;                        // 1024
  float* part  = ws + 1024;                 // 8*1024*128
  float* h1    = part + 8 * NN * DD;        // 131072
  float* h2    = h1 + NN * DD;              // 131072
  float* Aib   = h2 + NN * DD;              // 131072
  float* Bmat  = Aib + NN * DD;             // 131072

  k_rowsum<<<NN, 256, 0, stream>>>(adj, rsinv);
  // layer 1
  k_adjgemm<<<512, 256, 0, stream>>>(adj, node_feat, part);
  k_dense2f<<<512, 256, 0, stream>>>(node_feat, part, rsinv, W_g1, b_g1, h1);
  // layer 2
  k_adjgemm<<<512, 256, 0, stream>>>(adj, h1, part);
  k_dense2f<<<512, 256, 0, stream>>>(h1, part, rsinv, W_g2, b_g2, h2);
  // head precompute
  k_ab<<<512, 256, 0, stream>>>(h2, W_c1, b_c1, Aib, Bmat);
  // fused edge stage: 1024 blocks x 4 waves; wave = 16 j x 16 i
  k_edge<<<1024, 256, 0, stream>>>(edge_feat, W_c1, W_c2, b_c2, Aib, Bmat, out);
}

// Round 7
// 139.937 us; speedup vs baseline: 1.1595x; 1.1595x over previous
//
#include <hip/hip_runtime.h>
#include <hip/hip_bf16.h>
#include <stdint.h>

constexpr int NN = 1024;   // nodes
constexpr int DD = 128;    // NODE_DIM == HID
constexpr int EDIM = 32;   // EDGE_DIM
constexpr int NR = 16;     // NREL

using short4v = __attribute__((ext_vector_type(4))) short;
using short8v = __attribute__((ext_vector_type(8))) short;
using f32x4   = __attribute__((ext_vector_type(4))) float;

__device__ __forceinline__ short f2bf(float x) {
  __hip_bfloat16 h = __float2bfloat16(x);   // RNE
  return __builtin_bit_cast(short, h);
}

// async global->LDS, 16B per lane. LDS dest = wave-uniform base + lane*16 (m104);
// global src is per-lane. Low 32 bits of a generic LDS pointer are the offset.
__device__ __forceinline__ void gl_lds16(const void* g, void* l) {
  __builtin_amdgcn_global_load_lds(
      (const __attribute__((address_space(1))) unsigned int*)(uintptr_t)g,
      (__attribute__((address_space(3))) unsigned int*)(uint32_t)(uintptr_t)l,
      16, 0, 0);
}

// ---------------- K1: rsinv[i] = 1/(rowsum(adj[i]) + 1e-6) ----------------
__global__ __launch_bounds__(256) void k_rowsum(const float* __restrict__ adj,
                                                float* __restrict__ rsinv) {
  int i = blockIdx.x, t = threadIdx.x;
  const float4* row = (const float4*)(adj + (size_t)i * NN);
  float4 v = row[t];
  float s = v.x + v.y + v.z + v.w;
  #pragma unroll
  for (int off = 32; off > 0; off >>= 1) s += __shfl_down(s, off, 64);
  __shared__ float red[4];
  if ((t & 63) == 0) red[t >> 6] = s;
  __syncthreads();
  if (t == 0) rsinv[i] = 1.0f / (red[0] + red[1] + red[2] + red[3] + 1e-6f);
}

// ---------------- K2a: partial[kc][i][h] ----------------
__global__ __launch_bounds__(256) void k_adjgemm(const float* __restrict__ adj,
                                                 const float* __restrict__ X,
                                                 float* __restrict__ part) {
  __shared__ float sadj[16][128];
  int t = threadIdx.x;
  int ic = blockIdx.x & 63, kc = blockIdx.x >> 6;
  int i0 = ic * 16, k0 = kc * 128;
  {
    int il = t >> 4;
    int kl = (t & 15) * 8;
    const float4* src = (const float4*)(adj + (size_t)(i0 + il) * NN + k0 + kl);
    *(float4*)&sadj[il][kl]     = src[0];
    *(float4*)&sadj[il][kl + 4] = src[1];
  }
  __syncthreads();
  int h = t & 127, ii = t >> 7;
  float acc[8] = {0,0,0,0,0,0,0,0};
  for (int k = 0; k < 128; k += 4) {
    float x0 = X[(size_t)(k0 + k) * DD + h];
    float x1 = X[(size_t)(k0 + k + 1) * DD + h];
    float x2 = X[(size_t)(k0 + k + 2) * DD + h];
    float x3 = X[(size_t)(k0 + k + 3) * DD + h];
    #pragma unroll
    for (int m = 0; m < 8; ++m) {
      int il = ii + m * 2;
      float4 a = *(const float4*)&sadj[il][k];
      acc[m] += a.x * x0 + a.y * x1 + a.z * x2 + a.w * x3;
    }
  }
  #pragma unroll
  for (int m = 0; m < 8; ++m)
    part[((size_t)kc * NN + (i0 + ii + m * 2)) * DD + h] = acc[m];
}

// ---------------- K3/K5 (fused aggfin+dense) ----------------
__global__ __launch_bounds__(256) void k_dense2f(const float* __restrict__ X,
                                                 const float* __restrict__ part,
                                                 const float* __restrict__ rsinv,
                                                 const float* __restrict__ W,
                                                 const float* __restrict__ b,
                                                 float* __restrict__ out) {
  __shared__ float sagg[2][128];
  int t = threadIdx.x;
  int ig = t >> 7, h = t & 127;
  int i = blockIdx.x * 2 + ig;
  {
    float s = 0.f;
    #pragma unroll
    for (int kc = 0; kc < 8; ++kc) s += part[(size_t)kc * NN * DD + (size_t)i * DD + h];
    sagg[ig][h] = s * rsinv[i];
  }
  __syncthreads();
  const float4* xr = (const float4*)(X + (size_t)i * DD);
  const float4* ar = (const float4*)(&sagg[ig][0]);
  const float4* w1 = (const float4*)(W + (size_t)h * 256);
  const float4* w2 = (const float4*)(W + (size_t)h * 256 + DD);
  float acc = b[h];
  #pragma unroll 8
  for (int k = 0; k < 32; ++k) {
    float4 x = xr[k], w = w1[k];
    acc += x.x * w.x + x.y * w.y + x.z * w.z + x.w * w.w;
  }
  #pragma unroll 8
  for (int k = 0; k < 32; ++k) {
    float4 y = ar[k], w = w2[k];
    acc += y.x * w.x + y.y * w.y + y.z * w.z + y.w * w.w;
  }
  out[(size_t)i * DD + h] = fmaxf(acc, 0.f);
}

// ---------------- K6: Aib/Bmat precompute ----------------
__global__ __launch_bounds__(256) void k_ab(const float* __restrict__ h2,
                                            const float* __restrict__ Wc1,
                                            const float* __restrict__ bc1,
                                            float* __restrict__ Aib,
                                            float* __restrict__ Bmat) {
  int t = threadIdx.x;
  int i = blockIdx.x * 2 + (t >> 7), h = t & 127;
  const float4* xr = (const float4*)(h2 + (size_t)i * DD);
  const float4* wa = (const float4*)(Wc1 + (size_t)h * 288);
  const float4* wb = (const float4*)(Wc1 + (size_t)h * 288 + 128);
  float aa = bc1[h], bb = 0.f;
  #pragma unroll 8
  for (int k = 0; k < 32; ++k) {
    float4 x = xr[k];
    float4 a = wa[k], b2 = wb[k];
    aa += x.x * a.x + x.y * a.y + x.z * a.z + x.w * a.w;
    bb += x.x * b2.x + x.y * b2.y + x.z * b2.z + x.w * b2.w;
  }
  Aib[(size_t)i * DD + h] = aa;
  Bmat[(size_t)i * DD + h] = bb;
}

// ---------------- K7: fused edge stage (v7) ----------------
// Block: 16 i x 64 j; wave w: j = jg*64 + w*16 + c, bodies T=0..15 -> i0+T.
// Edge tiles (2KB) staged via glds into a 3-slot ring, distance-3 prefetch.
// Edge LDS reads are INSIDE inline asm (invisible to compiler-waitcnt), with
// our counted vmcnt + lgkmcnt(0) (lgkm0 also makes the same-slot glds refill
// WAR-safe). vmcnt ledger, conservative under any intra-body VMEM reorder:
//   B0=4, B1=5, B2=6, steady=6.  Stores 1/body, glds 2/body.
// Source-side XOR swizzle involution: LDS[X] = tile[X ^ (((X>>7)&7)<<4)].

#define EDGE_BODY(T, OFF, VMN) do {                                           \
    float4 e0_, e1_;                                                          \
    asm volatile("s_waitcnt vmcnt(" #VMN ")\n\t"                              \
                 "ds_read_b128 %0, %2 offset:" #OFF "\n\t"                    \
                 "ds_read_b128 %1, %3 offset:" #OFF "\n\t"                    \
                 "s_waitcnt lgkmcnt(0)"                                       \
                 : "=&v"(e0_), "=&v"(e1_)                                     \
                 : "v"(ea0), "v"(ea1)                                         \
                 : "memory");                                                 \
    __builtin_amdgcn_sched_barrier(0);                                        \
    { int tpf_ = (T) + 3 > 15 ? 15 : (T) + 3;                                 \
      const char* src_ = ebl + (size_t)tpf_ * 131072;                         \
      gl_lds16(src_, esw + (OFF));                                            \
      gl_lds16(src_ + 1024, esw + (OFF) + 1024); }                            \
    __builtin_amdgcn_sched_barrier(0);                                        \
    short8v ef_;                                                              \
    ef_[0]=f2bf(e0_.x); ef_[1]=f2bf(e0_.y); ef_[2]=f2bf(e0_.z); ef_[3]=f2bf(e0_.w); \
    ef_[4]=f2bf(e1_.x); ef_[5]=f2bf(e1_.y); ef_[6]=f2bf(e1_.z); ef_[7]=f2bf(e1_.w); \
    int i_ = i0 + (T);                                                        \
    const float* ap_ = aibs + (T) * 128 + 4 * g;                              \
    _Pragma("unroll")                                                         \
    for (int n = 0; n < 8; ++n) {                                             \
      float4 av_ = *(const float4*)(ap_ + 16 * n);                            \
      f32x4 ci_;                                                              \
      ci_[0] = av_.x + bjv[n].x; ci_[1] = av_.y + bjv[n].y;                   \
      ci_[2] = av_.z + bjv[n].z; ci_[3] = av_.w + bjv[n].w;                   \
      f32x4 acc_ = __builtin_amdgcn_mfma_f32_16x16x32_bf16(weF[n], ef_, ci_, 0, 0, 0); \
      short4v pk_;                                                            \
      pk_[0] = f2bf(fmaxf(acc_[0], 0.f)); pk_[1] = f2bf(fmaxf(acc_[1], 0.f)); \
      pk_[2] = f2bf(fmaxf(acc_[2], 0.f)); pk_[3] = f2bf(fmaxf(acc_[3], 0.f)); \
      *(short4v*)(psm + (((n >> 1) << 10) + ((n & 1) << 9) + wroff)) = pk_;   \
    }                                                                         \
    f32x4 acc2_;                                                              \
    acc2_[0] = bc2v.x; acc2_[1] = bc2v.y; acc2_[2] = bc2v.z; acc2_[3] = bc2v.w; \
    _Pragma("unroll")                                                         \
    for (int kk = 0; kk < 4; ++kk) {                                          \
      short8v pb_ = *(short8v*)(psm + ((kk << 10) + rdP));                    \
      acc2_ = __builtin_amdgcn_mfma_f32_16x16x32_bf16(wcF[kk], pb_, acc2_, 0, 0, 0); \
    }                                                                         \
    bool diag_ = (j == i_);                                                   \
    float4 o_;                                                                \
    o_.x = diag_ ? 0.f : acc2_[0];                                            \
    o_.y = diag_ ? 0.f : acc2_[1];                                            \
    o_.z = diag_ ? 0.f : acc2_[2];                                            \
    o_.w = diag_ ? 0.f : acc2_[3];                                            \
    *(float4*)(out + ((size_t)i_ * NN + j) * NR + 4 * g) = o_;                \
  } while (0)

__global__ __launch_bounds__(256, 3) void k_edge(const float* __restrict__ edge,
                                                 const float* __restrict__ Wc1,
                                                 const float* __restrict__ Wc2,
                                                 const float* __restrict__ bc2,
                                                 const float* __restrict__ Aib,
                                                 const float* __restrict__ Bmat,
                                                 float* __restrict__ out) {
  __shared__ __align__(16) char esm[4][3][2048];    // 24 KB edge ring (per wave x 3 slots)
  __shared__ __align__(16) char psm_all[4][4096];   // 16 KB P tiles
  __shared__ __align__(16) float aibs[16 * 128];    // 8 KB Aib panel   -> 48 KB total
  int tid = threadIdx.x;
  int w = tid >> 6, lane = tid & 63;
  int c = lane & 15, g = lane >> 4;
  int ig = blockIdx.x >> 4, jg = blockIdx.x & 15;
  int i0 = ig * 16;
  int j0w = jg * 64 + w * 16;
  int j = j0w + c;

  // stage Aib panel (16 i x 128 h) into LDS; only barrier in the kernel
  {
    int ii = tid >> 4, h8 = (tid & 15) * 8;
    const float4* s = (const float4*)(Aib + (size_t)(i0 + ii) * DD + h8);
    *(float4*)(aibs + ii * 128 + h8)     = s[0];
    *(float4*)(aibs + ii * 128 + h8 + 4) = s[1];
  }
  __syncthreads();

  // We fragments: A1[m=c][k=8g+jj] = Wc1[16n+c][256+8g+jj]
  short8v weF[8];
  #pragma unroll
  for (int n = 0; n < 8; ++n) {
    const float* p = Wc1 + (size_t)(16 * n + c) * 288 + 256 + 8 * g;
    float4 f0 = *(const float4*)p;
    float4 f1 = *(const float4*)(p + 4);
    short8v s;
    s[0]=f2bf(f0.x); s[1]=f2bf(f0.y); s[2]=f2bf(f0.z); s[3]=f2bf(f0.w);
    s[4]=f2bf(f1.x); s[5]=f2bf(f1.y); s[6]=f2bf(f1.z); s[7]=f2bf(f1.w);
    weF[n] = s;
  }
  // Wc2 fragments: A2[m=c][k=32kk+8g+jj]
  short8v wcF[4];
  #pragma unroll
  for (int kk = 0; kk < 4; ++kk) {
    const float* p = Wc2 + (size_t)c * DD + 32 * kk + 8 * g;
    float4 f0 = *(const float4*)p;
    float4 f1 = *(const float4*)(p + 4);
    short8v s;
    s[0]=f2bf(f0.x); s[1]=f2bf(f0.y); s[2]=f2bf(f0.z); s[3]=f2bf(f0.w);
    s[4]=f2bf(f1.x); s[5]=f2bf(f1.y); s[6]=f2bf(f1.z); s[7]=f2bf(f1.w);
    wcF[kk] = s;
  }
  float4 bc2v = *(const float4*)(bc2 + 4 * g);
  // Bmat for this lane's j, reused across all 16 i's
  float4 bjv[8];
  #pragma unroll
  for (int n = 0; n < 8; ++n)
    bjv[n] = *(const float4*)(Bmat + (size_t)j * DD + 16 * n + 4 * g);

  char* esw = &esm[w][0][0];
  char* psm = &psm_all[w][0];
  // per-lane swizzled source offset within a tile (involution on bits 4-6)
  const char* ebl = (const char*)edge + ((size_t)i0 * NN + j0w) * (EDIM * 4)
                    + ((lane * 16) ^ (((lane >> 3) & 7) << 4));
  // LDS read addrs for this lane's edge slice (same involution); slot via offset:
  int rd0 = c * 128 + ((g * 32)      ^ ((c & 7) << 4));
  int rd1 = c * 128 + ((g * 32 + 16) ^ ((c & 7) << 4));
  int ldsb = (int)(uint32_t)(uintptr_t)esw;
  int ea0 = ldsb + rd0;
  int ea1 = ldsb + rd1;
  // P-tile write/read offsets (derived conflict-free transpose layout)
  int wroff = (c << 4) + ((g & 1) << 3) + ((g >> 1) << 8);
  int rdP   = (g << 8) + (c << 4);

  // prologue: stage tiles 0,1,2 into slots 0,1,2
  gl_lds16(ebl,                  esw);
  gl_lds16(ebl + 1024,           esw + 1024);
  gl_lds16(ebl + 131072,         esw + 2048);
  gl_lds16(ebl + 131072 + 1024,  esw + 3072);
  gl_lds16(ebl + 262144,         esw + 4096);
  gl_lds16(ebl + 262144 + 1024,  esw + 5120);

  EDGE_BODY(0, 0, 4);
  EDGE_BODY(1, 2048, 5);
  EDGE_BODY(2, 4096, 6);
  #pragma unroll 1
  for (int t = 3; t < 15; t += 3) {
    EDGE_BODY(t,     0, 6);
    EDGE_BODY(t + 1, 2048, 6);
    EDGE_BODY(t + 2, 4096, 6);
  }
  EDGE_BODY(15, 0, 6);
}

extern "C" void kernel_launch(void* const* d_in, const int* in_sizes, int n_in,
                              void* d_out, int out_size, void* d_ws, size_t ws_size,
                              hipStream_t stream) {
  const float* node_feat = (const float*)d_in[0];
  const float* edge_feat = (const float*)d_in[1];
  const float* adj  = (const float*)d_in[2];
  const float* W_g1 = (const float*)d_in[3];
  const float* b_g1 = (const float*)d_in[4];
  const float* W_g2 = (const float*)d_in[5];
  const float* b_g2 = (const float*)d_in[6];
  const float* W_c1 = (const float*)d_in[7];
  const float* b_c1 = (const float*)d_in[8];
  const float* W_c2 = (const float*)d_in[9];
  const float* b_c2 = (const float*)d_in[10];
  float* out = (float*)d_out;

  float* ws    = (float*)d_ws;
  float* rsinv = ws;                        // 1024
  float* part  = ws + 1024;                 // 8*1024*128
  float* h1    = part + 8 * NN * DD;        // 131072
  float* h2    = h1 + NN * DD;              // 131072
  float* Aib   = h2 + NN * DD;              // 131072
  float* Bmat  = Aib + NN * DD;             // 131072

  k_rowsum<<<NN, 256, 0, stream>>>(adj, rsinv);
  // layer 1
  k_adjgemm<<<512, 256, 0, stream>>>(adj, node_feat, part);
  k_dense2f<<<512, 256, 0, stream>>>(node_feat, part, rsinv, W_g1, b_g1, h1);
  // layer 2
  k_adjgemm<<<512, 256, 0, stream>>>(adj, h1, part);
  k_dense2f<<<512, 256, 0, stream>>>(h1, part, rsinv, W_g2, b_g2, h2);
  // head precompute
  k_ab<<<512, 256, 0, stream>>>(h2, W_c1, b_c1, Aib, Bmat);
  // fused edge stage: 1024 blocks x 4 waves; wave = 16 j x 16 i
  k_edge<<<1024, 256, 0, stream>>>(edge_feat, W_c1, W_c2, b_c2, Aib, Bmat, out);
}

// Round 8
// 129.459 us; speedup vs baseline: 1.2534x; 1.0809x over previous
//
#include <hip/hip_runtime.h>
#include <hip/hip_bf16.h>
#include <stdint.h>

constexpr int NN = 1024;   // nodes
constexpr int DD = 128;    // NODE_DIM == HID
constexpr int EDIM = 32;   // EDGE_DIM
constexpr int NR = 16;     // NREL

using short4v = __attribute__((ext_vector_type(4))) short;
using short8v = __attribute__((ext_vector_type(8))) short;
using f32x4   = __attribute__((ext_vector_type(4))) float;

__device__ __forceinline__ short f2bf(float x) {
  __hip_bfloat16 h = __float2bfloat16(x);   // RNE
  return __builtin_bit_cast(short, h);
}

// async global->LDS, 16B per lane. LDS dest = wave-uniform base + lane*16 (m104);
// global src is per-lane. Low 32 bits of a generic LDS pointer are the offset.
__device__ __forceinline__ void gl_lds16(const void* g, void* l) {
  __builtin_amdgcn_global_load_lds(
      (const __attribute__((address_space(1))) unsigned int*)(uintptr_t)g,
      (__attribute__((address_space(3))) unsigned int*)(uint32_t)(uintptr_t)l,
      16, 0, 0);
}

// ---------------- K2a: partial[kc][i][h] ----------------
__global__ __launch_bounds__(256) void k_adjgemm(const float* __restrict__ adj,
                                                 const float* __restrict__ X,
                                                 float* __restrict__ part) {
  __shared__ float sadj[16][128];
  int t = threadIdx.x;
  int ic = blockIdx.x & 63, kc = blockIdx.x >> 6;
  int i0 = ic * 16, k0 = kc * 128;
  {
    int il = t >> 4;
    int kl = (t & 15) * 8;
    const float4* src = (const float4*)(adj + (size_t)(i0 + il) * NN + k0 + kl);
    *(float4*)&sadj[il][kl]     = src[0];
    *(float4*)&sadj[il][kl + 4] = src[1];
  }
  __syncthreads();
  int h = t & 127, ii = t >> 7;
  float acc[8] = {0,0,0,0,0,0,0,0};
  for (int k = 0; k < 128; k += 4) {
    float x0 = X[(size_t)(k0 + k) * DD + h];
    float x1 = X[(size_t)(k0 + k + 1) * DD + h];
    float x2 = X[(size_t)(k0 + k + 2) * DD + h];
    float x3 = X[(size_t)(k0 + k + 3) * DD + h];
    #pragma unroll
    for (int m = 0; m < 8; ++m) {
      int il = ii + m * 2;
      float4 a = *(const float4*)&sadj[il][k];
      acc[m] += a.x * x0 + a.y * x1 + a.z * x2 + a.w * x3;
    }
  }
  #pragma unroll
  for (int m = 0; m < 8; ++m)
    part[((size_t)kc * NN + (i0 + ii + m * 2)) * DD + h] = acc[m];
}

// ---------------- K_dense1: rowsum + aggfin + dense layer1 ----------------
__global__ __launch_bounds__(256) void k_dense1(const float* __restrict__ X,
                                                const float* __restrict__ part,
                                                const float* __restrict__ adj,
                                                const float* __restrict__ W,
                                                const float* __restrict__ b,
                                                float* __restrict__ out,
                                                float* __restrict__ rsinv) {
  __shared__ float sagg[2][128];
  __shared__ float red[4];
  int t = threadIdx.x;
  int ig = t >> 7, h = t & 127;
  int i = blockIdx.x * 2 + ig;
  {   // rowsum(adj[i]) : 128 threads x 8 floats (adj is L2-hot from k_adjgemm)
    const float4* ar = (const float4*)(adj + (size_t)i * NN);
    float4 v0 = ar[h * 2], v1 = ar[h * 2 + 1];
    float s = v0.x + v0.y + v0.z + v0.w + v1.x + v1.y + v1.z + v1.w;
    #pragma unroll
    for (int off = 32; off > 0; off >>= 1) s += __shfl_down(s, off, 64);
    if ((t & 63) == 0) red[t >> 6] = s;
  }
  __syncthreads();
  float rs = 1.0f / (red[ig * 2] + red[ig * 2 + 1] + 1e-6f);
  if (h == 0) rsinv[i] = rs;
  {
    float ss = 0.f;
    #pragma unroll
    for (int kc = 0; kc < 8; ++kc) ss += part[(size_t)kc * NN * DD + (size_t)i * DD + h];
    sagg[ig][h] = ss * rs;
  }
  __syncthreads();
  const float4* xr = (const float4*)(X + (size_t)i * DD);
  const float4* ar = (const float4*)(&sagg[ig][0]);
  const float4* w1 = (const float4*)(W + (size_t)h * 256);
  const float4* w2 = (const float4*)(W + (size_t)h * 256 + DD);
  float acc = b[h];
  #pragma unroll 8
  for (int k = 0; k < 32; ++k) {
    float4 x = xr[k], w = w1[k];
    acc += x.x * w.x + x.y * w.y + x.z * w.z + x.w * w.w;
  }
  #pragma unroll 8
  for (int k = 0; k < 32; ++k) {
    float4 y = ar[k], w = w2[k];
    acc += y.x * w.x + y.y * w.y + y.z * w.z + y.w * w.w;
  }
  out[(size_t)i * DD + h] = fmaxf(acc, 0.f);
}

// ---------------- K_dense2ab: aggfin + dense layer2 + Aib/Bmat, fused ----------------
__global__ __launch_bounds__(256) void k_dense2ab(const float* __restrict__ X,
                                                  const float* __restrict__ part,
                                                  const float* __restrict__ rsinv,
                                                  const float* __restrict__ W,
                                                  const float* __restrict__ b,
                                                  const float* __restrict__ Wc1,
                                                  const float* __restrict__ bc1,
                                                  float* __restrict__ Aib,
                                                  float* __restrict__ Bmat) {
  __shared__ float sagg[2][128];
  __shared__ float sh2[2][128];
  int t = threadIdx.x;
  int ig = t >> 7, h = t & 127;
  int i = blockIdx.x * 2 + ig;
  {
    float ss = 0.f;
    #pragma unroll
    for (int kc = 0; kc < 8; ++kc) ss += part[(size_t)kc * NN * DD + (size_t)i * DD + h];
    sagg[ig][h] = ss * rsinv[i];
  }
  __syncthreads();
  {
    const float4* xr = (const float4*)(X + (size_t)i * DD);
    const float4* ar = (const float4*)(&sagg[ig][0]);
    const float4* w1 = (const float4*)(W + (size_t)h * 256);
    const float4* w2 = (const float4*)(W + (size_t)h * 256 + DD);
    float acc = b[h];
    #pragma unroll 8
    for (int k = 0; k < 32; ++k) {
      float4 x = xr[k], w = w1[k];
      acc += x.x * w.x + x.y * w.y + x.z * w.z + x.w * w.w;
    }
    #pragma unroll 8
    for (int k = 0; k < 32; ++k) {
      float4 y = ar[k], w = w2[k];
      acc += y.x * w.x + y.y * w.y + y.z * w.z + y.w * w.w;
    }
    sh2[ig][h] = fmaxf(acc, 0.f);
  }
  __syncthreads();
  // Aib/Bmat from the in-LDS h2 row
  const float4* xr = (const float4*)(&sh2[ig][0]);
  const float4* wa = (const float4*)(Wc1 + (size_t)h * 288);
  const float4* wb = (const float4*)(Wc1 + (size_t)h * 288 + 128);
  float aa = bc1[h], bb = 0.f;
  #pragma unroll 8
  for (int k = 0; k < 32; ++k) {
    float4 x = xr[k];
    float4 a = wa[k], b2 = wb[k];
    aa += x.x * a.x + x.y * a.y + x.z * a.z + x.w * a.w;
    bb += x.x * b2.x + x.y * b2.y + x.z * b2.z + x.w * b2.w;
  }
  Aib[(size_t)i * DD + h] = aa;
  Bmat[(size_t)i * DD + h] = bb;
}

// ---------------- K7: fused edge stage (v8) ----------------
// Block: 16 i x 64 j; wave w: j = jg*64 + w*16 + c, bodies T=0..15 -> i0+T.
// 5-slot edge ring (glds, distance-5), deferred GEMM2 (body T runs GEMM1_T then
// GEMM2_{T-1} from dbuf P), stores batched x4 (flush at bodies 4/8/12 + epilogue)
// so counted-vmcnt waits never sit behind a young store in the VMEM FIFO.
// Ledger (order pinned by asm + sched_barriers; per body: [wait][edge ds_read]
// [glds x2 if PF][GEMM1][GEMM2_{T-1}][flush?]):
//   bodies 0-4: vmcnt(8); 5-11: 12; 12: 10; 13: 12; 14: 6; 15: 4.
// Source-side XOR swizzle involution: LDS[X] = tile[X ^ (((X>>7)&7)<<4)].

#define EDGE_BODY(T, OFF, VMN, PF) do {                                       \
    float4 e0_, e1_;                                                          \
    asm volatile("s_waitcnt vmcnt(" #VMN ")\n\t"                              \
                 "ds_read_b128 %0, %2 offset:" #OFF "\n\t"                    \
                 "ds_read_b128 %1, %3 offset:" #OFF "\n\t"                    \
                 "s_waitcnt lgkmcnt(0)"                                       \
                 : "=&v"(e0_), "=&v"(e1_)                                     \
                 : "v"(ea0), "v"(ea1)                                         \
                 : "memory");                                                 \
    __builtin_amdgcn_sched_barrier(0);                                        \
    if (PF) {                                                                 \
      const char* src_ = ebl + (size_t)((T) + 5) * 131072;                    \
      gl_lds16(src_, esw + (OFF));                                            \
      gl_lds16(src_ + 1024, esw + (OFF) + 1024);                              \
    }                                                                         \
    __builtin_amdgcn_sched_barrier(0);                                        \
    short8v ef_;                                                              \
    ef_[0]=f2bf(e0_.x); ef_[1]=f2bf(e0_.y); ef_[2]=f2bf(e0_.z); ef_[3]=f2bf(e0_.w); \
    ef_[4]=f2bf(e1_.x); ef_[5]=f2bf(e1_.y); ef_[6]=f2bf(e1_.z); ef_[7]=f2bf(e1_.w); \
    char* pw_ = psm + (((T) & 1) << 12);                                      \
    const float* ap_ = aibs + (T) * 128 + 4 * g;                              \
    _Pragma("unroll")                                                         \
    for (int n = 0; n < 8; ++n) {                                             \
      float4 av_ = *(const float4*)(ap_ + 16 * n);                            \
      f32x4 ci_;                                                              \
      ci_[0] = av_.x + bjv[n].x; ci_[1] = av_.y + bjv[n].y;                   \
      ci_[2] = av_.z + bjv[n].z; ci_[3] = av_.w + bjv[n].w;                   \
      f32x4 acc_ = __builtin_amdgcn_mfma_f32_16x16x32_bf16(weF[n], ef_, ci_, 0, 0, 0); \
      short4v pk_;                                                            \
      pk_[0] = f2bf(fmaxf(acc_[0], 0.f)); pk_[1] = f2bf(fmaxf(acc_[1], 0.f)); \
      pk_[2] = f2bf(fmaxf(acc_[2], 0.f)); pk_[3] = f2bf(fmaxf(acc_[3], 0.f)); \
      *(short4v*)(pw_ + (((n >> 1) << 10) + ((n & 1) << 9) + wroff)) = pk_;   \
    }                                                                         \
  } while (0)

#define G2(G2T, OREG) do {                                                    \
    f32x4 a2_;                                                                \
    a2_[0] = bc2v.x; a2_[1] = bc2v.y; a2_[2] = bc2v.z; a2_[3] = bc2v.w;       \
    const char* pp_ = psm + (((G2T) & 1) << 12);                              \
    _Pragma("unroll")                                                         \
    for (int kk = 0; kk < 4; ++kk) {                                          \
      short8v pb_ = *(const short8v*)(pp_ + ((kk << 10) + rdP));              \
      a2_ = __builtin_amdgcn_mfma_f32_16x16x32_bf16(wcF[kk], pb_, a2_, 0, 0, 0); \
    }                                                                         \
    bool dg_ = (j == i0 + (G2T));                                             \
    OREG.x = dg_ ? 0.f : a2_[0];                                              \
    OREG.y = dg_ ? 0.f : a2_[1];                                              \
    OREG.z = dg_ ? 0.f : a2_[2];                                              \
    OREG.w = dg_ ? 0.f : a2_[3];                                              \
  } while (0)

#define FLUSH(BASE) do {                                                      \
    *(float4*)(out + ((size_t)(i0 + (BASE) + 0) * NN + j) * NR + 4 * g) = o0; \
    *(float4*)(out + ((size_t)(i0 + (BASE) + 1) * NN + j) * NR + 4 * g) = o1; \
    *(float4*)(out + ((size_t)(i0 + (BASE) + 2) * NN + j) * NR + 4 * g) = o2; \
    *(float4*)(out + ((size_t)(i0 + (BASE) + 3) * NN + j) * NR + 4 * g) = o3; \
  } while (0)

__global__ __launch_bounds__(256, 2) void k_edge(const float* __restrict__ edge,
                                                 const float* __restrict__ Wc1,
                                                 const float* __restrict__ Wc2,
                                                 const float* __restrict__ bc2,
                                                 const float* __restrict__ Aib,
                                                 const float* __restrict__ Bmat,
                                                 float* __restrict__ out) {
  __shared__ __align__(16) char esm[4][5][2048];    // 40 KB edge ring (per wave x 5 slots)
  __shared__ __align__(16) char psm_all[4][2][4096];// 32 KB P tiles (dbuf per wave)
  __shared__ __align__(16) float aibs[16 * 128];    // 8 KB Aib panel  -> 80 KB total
  int tid = threadIdx.x;
  int w = tid >> 6, lane = tid & 63;
  int c = lane & 15, g = lane >> 4;
  int ig = blockIdx.x >> 4, jg = blockIdx.x & 15;
  int i0 = ig * 16;
  int j0w = jg * 64 + w * 16;
  int j = j0w + c;

  // stage Aib panel (16 i x 128 h) into LDS
  {
    int ii = tid >> 4, h8 = (tid & 15) * 8;
    const float4* s = (const float4*)(Aib + (size_t)(i0 + ii) * DD + h8);
    *(float4*)(aibs + ii * 128 + h8)     = s[0];
    *(float4*)(aibs + ii * 128 + h8 + 4) = s[1];
  }

  // We fragments: A1[m=c][k=8g+jj] = Wc1[16n+c][256+8g+jj]
  short8v weF[8];
  #pragma unroll
  for (int n = 0; n < 8; ++n) {
    const float* p = Wc1 + (size_t)(16 * n + c) * 288 + 256 + 8 * g;
    float4 f0 = *(const float4*)p;
    float4 f1 = *(const float4*)(p + 4);
    short8v s;
    s[0]=f2bf(f0.x); s[1]=f2bf(f0.y); s[2]=f2bf(f0.z); s[3]=f2bf(f0.w);
    s[4]=f2bf(f1.x); s[5]=f2bf(f1.y); s[6]=f2bf(f1.z); s[7]=f2bf(f1.w);
    weF[n] = s;
  }
  // Wc2 fragments: A2[m=c][k=32kk+8g+jj]
  short8v wcF[4];
  #pragma unroll
  for (int kk = 0; kk < 4; ++kk) {
    const float* p = Wc2 + (size_t)c * DD + 32 * kk + 8 * g;
    float4 f0 = *(const float4*)p;
    float4 f1 = *(const float4*)(p + 4);
    short8v s;
    s[0]=f2bf(f0.x); s[1]=f2bf(f0.y); s[2]=f2bf(f0.z); s[3]=f2bf(f0.w);
    s[4]=f2bf(f1.x); s[5]=f2bf(f1.y); s[6]=f2bf(f1.z); s[7]=f2bf(f1.w);
    wcF[kk] = s;
  }
  float4 bc2v = *(const float4*)(bc2 + 4 * g);
  // Bmat for this lane's j, reused across all 16 i's
  float4 bjv[8];
  #pragma unroll
  for (int n = 0; n < 8; ++n)
    bjv[n] = *(const float4*)(Bmat + (size_t)j * DD + 16 * n + 4 * g);

  // barrier drains ALL outstanding VMEM (syncthreads emits vmcnt(0)) ->
  // the counted ledger below starts from an empty FIFO.
  __syncthreads();

  char* esw = &esm[w][0][0];
  char* psm = &psm_all[w][0][0];
  // per-lane swizzled source offset within a tile (involution on bits 4-6)
  const char* ebl = (const char*)edge + ((size_t)i0 * NN + j0w) * (EDIM * 4)
                    + ((lane * 16) ^ (((lane >> 3) & 7) << 4));
  // LDS read addrs for this lane's edge slice (same involution); slot via offset:
  int rd0 = c * 128 + ((g * 32)      ^ ((c & 7) << 4));
  int rd1 = c * 128 + ((g * 32 + 16) ^ ((c & 7) << 4));
  int ldsb = (int)(uint32_t)(uintptr_t)esw;
  int ea0 = ldsb + rd0;
  int ea1 = ldsb + rd1;
  // P-tile write/read offsets (derived conflict-free transpose layout)
  int wroff = (c << 4) + ((g & 1) << 3) + ((g >> 1) << 8);
  int rdP   = (g << 8) + (c << 4);

  float4 o0, o1, o2, o3;

  // prologue: stage tiles 0..4 into slots 0..4 (10 glds)
  gl_lds16(ebl,                      esw);
  gl_lds16(ebl + 1024,               esw + 1024);
  gl_lds16(ebl + 1 * 131072,         esw + 2048);
  gl_lds16(ebl + 1 * 131072 + 1024,  esw + 3072);
  gl_lds16(ebl + 2 * 131072,         esw + 4096);
  gl_lds16(ebl + 2 * 131072 + 1024,  esw + 5120);
  gl_lds16(ebl + 3 * 131072,         esw + 6144);
  gl_lds16(ebl + 3 * 131072 + 1024,  esw + 7168);
  gl_lds16(ebl + 4 * 131072,         esw + 8192);
  gl_lds16(ebl + 4 * 131072 + 1024,  esw + 9216);

  EDGE_BODY(0,  0,    8, 1);
  EDGE_BODY(1,  2048, 8, 1);  G2(0, o0);
  EDGE_BODY(2,  4096, 8, 1);  G2(1, o1);
  EDGE_BODY(3,  6144, 8, 1);  G2(2, o2);
  EDGE_BODY(4,  8192, 8, 1);  G2(3, o3);  FLUSH(0);
  EDGE_BODY(5,  0,    12, 1); G2(4, o0);
  EDGE_BODY(6,  2048, 12, 1); G2(5, o1);
  EDGE_BODY(7,  4096, 12, 1); G2(6, o2);
  EDGE_BODY(8,  6144, 12, 1); G2(7, o3);  FLUSH(4);
  EDGE_BODY(9,  8192, 12, 1); G2(8, o0);
  EDGE_BODY(10, 0,    12, 1); G2(9, o1);
  EDGE_BODY(11, 2048, 12, 0); G2(10, o2);
  EDGE_BODY(12, 4096, 10, 0); G2(11, o3); FLUSH(8);
  EDGE_BODY(13, 6144, 12, 0); G2(12, o0);
  EDGE_BODY(14, 8192, 6, 0);  G2(13, o1);
  EDGE_BODY(15, 0,    4, 0);  G2(14, o2);
  G2(15, o3); FLUSH(12);
}

extern "C" void kernel_launch(void* const* d_in, const int* in_sizes, int n_in,
                              void* d_out, int out_size, void* d_ws, size_t ws_size,
                              hipStream_t stream) {
  const float* node_feat = (const float*)d_in[0];
  const float* edge_feat = (const float*)d_in[1];
  const float* adj  = (const float*)d_in[2];
  const float* W_g1 = (const float*)d_in[3];
  const float* b_g1 = (const float*)d_in[4];
  const float* W_g2 = (const float*)d_in[5];
  const float* b_g2 = (const float*)d_in[6];
  const float* W_c1 = (const float*)d_in[7];
  const float* b_c1 = (const float*)d_in[8];
  const float* W_c2 = (const float*)d_in[9];
  const float* b_c2 = (const float*)d_in[10];
  float* out = (float*)d_out;

  float* ws    = (float*)d_ws;
  float* rsinv = ws;                        // 1024
  float* part  = ws + 1024;                 // 8*1024*128
  float* h1    = part + 8 * NN * DD;        // 131072
  float* Aib   = h1 + NN * DD;              // 131072
  float* Bmat  = Aib + NN * DD;             // 131072

  // layer 1 (rowsum fused into dense1)
  k_adjgemm<<<512, 256, 0, stream>>>(adj, node_feat, part);
  k_dense1<<<512, 256, 0, stream>>>(node_feat, part, adj, W_g1, b_g1, h1, rsinv);
  // layer 2 (+ Aib/Bmat head precompute fused)
  k_adjgemm<<<512, 256, 0, stream>>>(adj, h1, part);
  k_dense2ab<<<512, 256, 0, stream>>>(h1, part, rsinv, W_g2, b_g2, W_c1, b_c1, Aib, Bmat);
  // fused edge stage: 1024 blocks x 4 waves; wave = 16 j x 16 i
  k_edge<<<1024, 256, 0, stream>>>(edge_feat, W_c1, W_c2, b_c2, Aib, Bmat, out);
}

// Round 10
// 127.821 us; speedup vs baseline: 1.2694x; 1.0128x over previous
//
#include <hip/hip_runtime.h>
#include <hip/hip_bf16.h>
#include <stdint.h>

constexpr int NN = 1024;   // nodes
constexpr int DD = 128;    // NODE_DIM == HID
constexpr int EDIM = 32;   // EDGE_DIM
constexpr int NR = 16;     // NREL

using short4v = __attribute__((ext_vector_type(4))) short;
using short8v = __attribute__((ext_vector_type(8))) short;
using f32x4   = __attribute__((ext_vector_type(4))) float;

__device__ __forceinline__ short f2bf(float x) {
  __hip_bfloat16 h = __float2bfloat16(x);   // RNE
  return __builtin_bit_cast(short, h);
}

__device__ __forceinline__ void nt_store4(float* p, const float4& v) {
  f32x4 t;
  t[0] = v.x; t[1] = v.y; t[2] = v.z; t[3] = v.w;
  __builtin_nontemporal_store(t, (f32x4*)p);
}

// async global->LDS, 16B per lane. LDS dest = wave-uniform base + lane*16 (m104);
// global src is per-lane. Low 32 bits of a generic LDS pointer are the offset.
__device__ __forceinline__ void gl_lds16(const void* g, void* l) {
  __builtin_amdgcn_global_load_lds(
      (const __attribute__((address_space(1))) unsigned int*)(uintptr_t)g,
      (__attribute__((address_space(3))) unsigned int*)(uint32_t)(uintptr_t)l,
      16, 0, 0);
}

// ---------------- K2a v2: partial[kc][i][h] (float4-over-h, b32 adj broadcast) ----
// Per k: 2 ds_read_b32 (conflict-free via pad-136) + 1 global b128 + 8 FMA.
__global__ __launch_bounds__(256) void k_adjgemm(const float* __restrict__ adj,
                                                 const float* __restrict__ X,
                                                 float* __restrict__ part) {
  __shared__ float sadj[16][136];          // pad 136: bank = (2*il + k) % 32, distinct
  int t = threadIdx.x;
  int ic = blockIdx.x & 63, kc = blockIdx.x >> 6;
  int i0 = ic * 16, k0 = kc * 128;
  {
    int il = t >> 4;
    int kl = (t & 15) * 8;
    const float4* src = (const float4*)(adj + (size_t)(i0 + il) * NN + k0 + kl);
    *(float4*)&sadj[il][kl]     = src[0];
    *(float4*)&sadj[il][kl + 4] = src[1];
  }
  __syncthreads();
  int hq = (t & 31) * 4;                   // h quad
  int ir = t >> 5;                         // 0..7
  float4 acc0 = {0,0,0,0}, acc1 = {0,0,0,0};
  const float* Xb = X + (size_t)k0 * DD + hq;
  #pragma unroll 4
  for (int k = 0; k < 128; ++k) {
    float4 xv = *(const float4*)(Xb + (size_t)k * DD);
    float a0 = sadj[ir][k];
    float a1 = sadj[ir + 8][k];
    acc0.x += a0 * xv.x; acc0.y += a0 * xv.y; acc0.z += a0 * xv.z; acc0.w += a0 * xv.w;
    acc1.x += a1 * xv.x; acc1.y += a1 * xv.y; acc1.z += a1 * xv.z; acc1.w += a1 * xv.w;
  }
  *(float4*)(part + ((size_t)kc * NN + (i0 + ir)) * DD + hq)     = acc0;
  *(float4*)(part + ((size_t)kc * NN + (i0 + ir + 8)) * DD + hq) = acc1;
}

// ---------------- K_dense1: rowsum + aggfin + dense layer1 ----------------
__global__ __launch_bounds__(256) void k_dense1(const float* __restrict__ X,
                                                const float* __restrict__ part,
                                                const float* __restrict__ adj,
                                                const float* __restrict__ W,
                                                const float* __restrict__ b,
                                                float* __restrict__ out,
                                                float* __restrict__ rsinv) {
  __shared__ float sagg[2][128];
  __shared__ float red[4];
  int t = threadIdx.x;
  int ig = t >> 7, h = t & 127;
  int i = blockIdx.x * 2 + ig;
  {   // rowsum(adj[i]) : 128 threads x 8 floats (adj is L2-hot from k_adjgemm)
    const float4* ar = (const float4*)(adj + (size_t)i * NN);
    float4 v0 = ar[h * 2], v1 = ar[h * 2 + 1];
    float s = v0.x + v0.y + v0.z + v0.w + v1.x + v1.y + v1.z + v1.w;
    #pragma unroll
    for (int off = 32; off > 0; off >>= 1) s += __shfl_down(s, off, 64);
    if ((t & 63) == 0) red[t >> 6] = s;
  }
  __syncthreads();
  float rs = 1.0f / (red[ig * 2] + red[ig * 2 + 1] + 1e-6f);
  if (h == 0) rsinv[i] = rs;
  {
    float ss = 0.f;
    #pragma unroll
    for (int kc = 0; kc < 8; ++kc) ss += part[(size_t)kc * NN * DD + (size_t)i * DD + h];
    sagg[ig][h] = ss * rs;
  }
  __syncthreads();
  const float4* xr = (const float4*)(X + (size_t)i * DD);
  const float4* ar = (const float4*)(&sagg[ig][0]);
  const float4* w1 = (const float4*)(W + (size_t)h * 256);
  const float4* w2 = (const float4*)(W + (size_t)h * 256 + DD);
  float acc = b[h];
  #pragma unroll 8
  for (int k = 0; k < 32; ++k) {
    float4 x = xr[k], w = w1[k];
    acc += x.x * w.x + x.y * w.y + x.z * w.z + x.w * w.w;
  }
  #pragma unroll 8
  for (int k = 0; k < 32; ++k) {
    float4 y = ar[k], w = w2[k];
    acc += y.x * w.x + y.y * w.y + y.z * w.z + y.w * w.w;
  }
  out[(size_t)i * DD + h] = fmaxf(acc, 0.f);
}

// ---------------- K_dense2ab: aggfin + dense layer2 + Aib/Bmat, fused ----------------
__global__ __launch_bounds__(256) void k_dense2ab(const float* __restrict__ X,
                                                  const float* __restrict__ part,
                                                  const float* __restrict__ rsinv,
                                                  const float* __restrict__ W,
                                                  const float* __restrict__ b,
                                                  const float* __restrict__ Wc1,
                                                  const float* __restrict__ bc1,
                                                  float* __restrict__ Aib,
                                                  float* __restrict__ Bmat) {
  __shared__ float sagg[2][128];
  __shared__ float sh2[2][128];
  int t = threadIdx.x;
  int ig = t >> 7, h = t & 127;
  int i = blockIdx.x * 2 + ig;
  {
    float ss = 0.f;
    #pragma unroll
    for (int kc = 0; kc < 8; ++kc) ss += part[(size_t)kc * NN * DD + (size_t)i * DD + h];
    sagg[ig][h] = ss * rsinv[i];
  }
  __syncthreads();
  {
    const float4* xr = (const float4*)(X + (size_t)i * DD);
    const float4* ar = (const float4*)(&sagg[ig][0]);
    const float4* w1 = (const float4*)(W + (size_t)h * 256);
    const float4* w2 = (const float4*)(W + (size_t)h * 256 + DD);
    float acc = b[h];
    #pragma unroll 8
    for (int k = 0; k < 32; ++k) {
      float4 x = xr[k], w = w1[k];
      acc += x.x * w.x + x.y * w.y + x.z * w.z + x.w * w.w;
    }
    #pragma unroll 8
    for (int k = 0; k < 32; ++k) {
      float4 y = ar[k], w = w2[k];
      acc += y.x * w.x + y.y * w.y + y.z * w.z + y.w * w.w;
    }
    sh2[ig][h] = fmaxf(acc, 0.f);
  }
  __syncthreads();
  // Aib/Bmat from the in-LDS h2 row
  const float4* xr = (const float4*)(&sh2[ig][0]);
  const float4* wa = (const float4*)(Wc1 + (size_t)h * 288);
  const float4* wb = (const float4*)(Wc1 + (size_t)h * 288 + 128);
  float aa = bc1[h], bb = 0.f;
  #pragma unroll 8
  for (int k = 0; k < 32; ++k) {
    float4 x = xr[k];
    float4 a = wa[k], b2 = wb[k];
    aa += x.x * a.x + x.y * a.y + x.z * a.z + x.w * a.w;
    bb += x.x * b2.x + x.y * b2.y + x.z * b2.z + x.w * b2.w;
  }
  Aib[(size_t)i * DD + h] = aa;
  Bmat[(size_t)i * DD + h] = bb;
}

// ---------------- K7: fused edge stage (v9 = v8 + nontemporal out stores) -------
// Block: 16 i x 64 j; wave w: j = jg*64 + w*16 + c, bodies T=0..15 -> i0+T.
// 5-slot edge ring (glds, distance-5), deferred GEMM2, stores batched x4 with
// nontemporal hint (out never re-read; don't write-allocate L2).
// Ledger: bodies 0-4 vmcnt(8); 5-11: 12; 12: 10; 13: 12; 14: 6; 15: 4.
// Source-side XOR swizzle involution: LDS[X] = tile[X ^ (((X>>7)&7)<<4)].

#define EDGE_BODY(T, OFF, VMN, PF) do {                                       \
    float4 e0_, e1_;                                                          \
    asm volatile("s_waitcnt vmcnt(" #VMN ")\n\t"                              \
                 "ds_read_b128 %0, %2 offset:" #OFF "\n\t"                    \
                 "ds_read_b128 %1, %3 offset:" #OFF "\n\t"                    \
                 "s_waitcnt lgkmcnt(0)"                                       \
                 : "=&v"(e0_), "=&v"(e1_)                                     \
                 : "v"(ea0), "v"(ea1)                                         \
                 : "memory");                                                 \
    __builtin_amdgcn_sched_barrier(0);                                        \
    if (PF) {                                                                 \
      const char* src_ = ebl + (size_t)((T) + 5) * 131072;                    \
      gl_lds16(src_, esw + (OFF));                                            \
      gl_lds16(src_ + 1024, esw + (OFF) + 1024);                              \
    }                                                                         \
    __builtin_amdgcn_sched_barrier(0);                                        \
    short8v ef_;                                                              \
    ef_[0]=f2bf(e0_.x); ef_[1]=f2bf(e0_.y); ef_[2]=f2bf(e0_.z); ef_[3]=f2bf(e0_.w); \
    ef_[4]=f2bf(e1_.x); ef_[5]=f2bf(e1_.y); ef_[6]=f2bf(e1_.z); ef_[7]=f2bf(e1_.w); \
    char* pw_ = psm + (((T) & 1) << 12);                                      \
    const float* ap_ = aibs + (T) * 128 + 4 * g;                              \
    _Pragma("unroll")                                                         \
    for (int n = 0; n < 8; ++n) {                                             \
      float4 av_ = *(const float4*)(ap_ + 16 * n);                            \
      f32x4 ci_;                                                              \
      ci_[0] = av_.x + bjv[n].x; ci_[1] = av_.y + bjv[n].y;                   \
      ci_[2] = av_.z + bjv[n].z; ci_[3] = av_.w + bjv[n].w;                   \
      f32x4 acc_ = __builtin_amdgcn_mfma_f32_16x16x32_bf16(weF[n], ef_, ci_, 0, 0, 0); \
      short4v pk_;                                                            \
      pk_[0] = f2bf(fmaxf(acc_[0], 0.f)); pk_[1] = f2bf(fmaxf(acc_[1], 0.f)); \
      pk_[2] = f2bf(fmaxf(acc_[2], 0.f)); pk_[3] = f2bf(fmaxf(acc_[3], 0.f)); \
      *(short4v*)(pw_ + (((n >> 1) << 10) + ((n & 1) << 9) + wroff)) = pk_;   \
    }                                                                         \
  } while (0)

#define G2(G2T, OREG) do {                                                    \
    f32x4 a2_;                                                                \
    a2_[0] = bc2v.x; a2_[1] = bc2v.y; a2_[2] = bc2v.z; a2_[3] = bc2v.w;       \
    const char* pp_ = psm + (((G2T) & 1) << 12);                              \
    _Pragma("unroll")                                                         \
    for (int kk = 0; kk < 4; ++kk) {                                          \
      short8v pb_ = *(const short8v*)(pp_ + ((kk << 10) + rdP));              \
      a2_ = __builtin_amdgcn_mfma_f32_16x16x32_bf16(wcF[kk], pb_, a2_, 0, 0, 0); \
    }                                                                         \
    bool dg_ = (j == i0 + (G2T));                                             \
    OREG.x = dg_ ? 0.f : a2_[0];                                              \
    OREG.y = dg_ ? 0.f : a2_[1];                                              \
    OREG.z = dg_ ? 0.f : a2_[2];                                              \
    OREG.w = dg_ ? 0.f : a2_[3];                                              \
  } while (0)

#define FLUSH(BASE) do {                                                      \
    nt_store4(out + ((size_t)(i0 + (BASE) + 0) * NN + j) * NR + 4 * g, o0);   \
    nt_store4(out + ((size_t)(i0 + (BASE) + 1) * NN + j) * NR + 4 * g, o1);   \
    nt_store4(out + ((size_t)(i0 + (BASE) + 2) * NN + j) * NR + 4 * g, o2);   \
    nt_store4(out + ((size_t)(i0 + (BASE) + 3) * NN + j) * NR + 4 * g, o3);   \
  } while (0)

__global__ __launch_bounds__(256, 2) void k_edge(const float* __restrict__ edge,
                                                 const float* __restrict__ Wc1,
                                                 const float* __restrict__ Wc2,
                                                 const float* __restrict__ bc2,
                                                 const float* __restrict__ Aib,
                                                 const float* __restrict__ Bmat,
                                                 float* __restrict__ out) {
  __shared__ __align__(16) char esm[4][5][2048];    // 40 KB edge ring (per wave x 5 slots)
  __shared__ __align__(16) char psm_all[4][2][4096];// 32 KB P tiles (dbuf per wave)
  __shared__ __align__(16) float aibs[16 * 128];    // 8 KB Aib panel  -> 80 KB total
  int tid = threadIdx.x;
  int w = tid >> 6, lane = tid & 63;
  int c = lane & 15, g = lane >> 4;
  int ig = blockIdx.x >> 4, jg = blockIdx.x & 15;
  int i0 = ig * 16;
  int j0w = jg * 64 + w * 16;
  int j = j0w + c;

  // stage Aib panel (16 i x 128 h) into LDS
  {
    int ii = tid >> 4, h8 = (tid & 15) * 8;
    const float4* s = (const float4*)(Aib + (size_t)(i0 + ii) * DD + h8);
    *(float4*)(aibs + ii * 128 + h8)     = s[0];
    *(float4*)(aibs + ii * 128 + h8 + 4) = s[1];
  }

  // We fragments: A1[m=c][k=8g+jj] = Wc1[16n+c][256+8g+jj]
  short8v weF[8];
  #pragma unroll
  for (int n = 0; n < 8; ++n) {
    const float* p = Wc1 + (size_t)(16 * n + c) * 288 + 256 + 8 * g;
    float4 f0 = *(const float4*)p;
    float4 f1 = *(const float4*)(p + 4);
    short8v s;
    s[0]=f2bf(f0.x); s[1]=f2bf(f0.y); s[2]=f2bf(f0.z); s[3]=f2bf(f0.w);
    s[4]=f2bf(f1.x); s[5]=f2bf(f1.y); s[6]=f2bf(f1.z); s[7]=f2bf(f1.w);
    weF[n] = s;
  }
  // Wc2 fragments: A2[m=c][k=32kk+8g+jj]
  short8v wcF[4];
  #pragma unroll
  for (int kk = 0; kk < 4; ++kk) {
    const float* p = Wc2 + (size_t)c * DD + 32 * kk + 8 * g;
    float4 f0 = *(const float4*)p;
    float4 f1 = *(const float4*)(p + 4);
    short8v s;
    s[0]=f2bf(f0.x); s[1]=f2bf(f0.y); s[2]=f2bf(f0.z); s[3]=f2bf(f0.w);
    s[4]=f2bf(f1.x); s[5]=f2bf(f1.y); s[6]=f2bf(f1.z); s[7]=f2bf(f1.w);
    wcF[kk] = s;
  }
  float4 bc2v = *(const float4*)(bc2 + 4 * g);
  // Bmat for this lane's j, reused across all 16 i's
  float4 bjv[8];
  #pragma unroll
  for (int n = 0; n < 8; ++n)
    bjv[n] = *(const float4*)(Bmat + (size_t)j * DD + 16 * n + 4 * g);

  // barrier drains ALL outstanding VMEM (syncthreads emits vmcnt(0)) ->
  // the counted ledger below starts from an empty FIFO.
  __syncthreads();

  char* esw = &esm[w][0][0];
  char* psm = &psm_all[w][0][0];
  // per-lane swizzled source offset within a tile (involution on bits 4-6)
  const char* ebl = (const char*)edge + ((size_t)i0 * NN + j0w) * (EDIM * 4)
                    + ((lane * 16) ^ (((lane >> 3) & 7) << 4));
  // LDS read addrs for this lane's edge slice (same involution); slot via offset:
  int rd0 = c * 128 + ((g * 32)      ^ ((c & 7) << 4));
  int rd1 = c * 128 + ((g * 32 + 16) ^ ((c & 7) << 4));
  int ldsb = (int)(uint32_t)(uintptr_t)esw;
  int ea0 = ldsb + rd0;
  int ea1 = ldsb + rd1;
  // P-tile write/read offsets (derived conflict-free transpose layout)
  int wroff = (c << 4) + ((g & 1) << 3) + ((g >> 1) << 8);
  int rdP   = (g << 8) + (c << 4);

  float4 o0, o1, o2, o3;

  // prologue: stage tiles 0..4 into slots 0..4 (10 glds)
  gl_lds16(ebl,                      esw);
  gl_lds16(ebl + 1024,               esw + 1024);
  gl_lds16(ebl + 1 * 131072,         esw + 2048);
  gl_lds16(ebl + 1 * 131072 + 1024,  esw + 3072);
  gl_lds16(ebl + 2 * 131072,         esw + 4096);
  gl_lds16(ebl + 2 * 131072 + 1024,  esw + 5120);
  gl_lds16(ebl + 3 * 131072,         esw + 6144);
  gl_lds16(ebl + 3 * 131072 + 1024,  esw + 7168);
  gl_lds16(ebl + 4 * 131072,         esw + 8192);
  gl_lds16(ebl + 4 * 131072 + 1024,  esw + 9216);

  EDGE_BODY(0,  0,    8, 1);
  EDGE_BODY(1,  2048, 8, 1);  G2(0, o0);
  EDGE_BODY(2,  4096, 8, 1);  G2(1, o1);
  EDGE_BODY(3,  6144, 8, 1);  G2(2, o2);
  EDGE_BODY(4,  8192, 8, 1);  G2(3, o3);  FLUSH(0);
  EDGE_BODY(5,  0,    12, 1); G2(4, o0);
  EDGE_BODY(6,  2048, 12, 1); G2(5, o1);
  EDGE_BODY(7,  4096, 12, 1); G2(6, o2);
  EDGE_BODY(8,  6144, 12, 1); G2(7, o3);  FLUSH(4);
  EDGE_BODY(9,  8192, 12, 1); G2(8, o0);
  EDGE_BODY(10, 0,    12, 1); G2(9, o1);
  EDGE_BODY(11, 2048, 12, 0); G2(10, o2);
  EDGE_BODY(12, 4096, 10, 0); G2(11, o3); FLUSH(8);
  EDGE_BODY(13, 6144, 12, 0); G2(12, o0);
  EDGE_BODY(14, 8192, 6, 0);  G2(13, o1);
  EDGE_BODY(15, 0,    4, 0);  G2(14, o2);
  G2(15, o3); FLUSH(12);
}

extern "C" void kernel_launch(void* const* d_in, const int* in_sizes, int n_in,
                              void* d_out, int out_size, void* d_ws, size_t ws_size,
                              hipStream_t stream) {
  const float* node_feat = (const float*)d_in[0];
  const float* edge_feat = (const float*)d_in[1];
  const float* adj  = (const float*)d_in[2];
  const float* W_g1 = (const float*)d_in[3];
  const float* b_g1 = (const float*)d_in[4];
  const float* W_g2 = (const float*)d_in[5];
  const float* b_g2 = (const float*)d_in[6];
  const float* W_c1 = (const float*)d_in[7];
  const float* b_c1 = (const float*)d_in[8];
  const float* W_c2 = (const float*)d_in[9];
  const float* b_c2 = (const float*)d_in[10];
  float* out = (float*)d_out;

  float* ws    = (float*)d_ws;
  float* rsinv = ws;                        // 1024
  float* part  = ws + 1024;                 // 8*1024*128
  float* h1    = part + 8 * NN * DD;        // 131072
  float* Aib   = h1 + NN * DD;              // 131072
  float* Bmat  = Aib + NN * DD;             // 131072

  // layer 1 (rowsum fused into dense1)
  k_adjgemm<<<512, 256, 0, stream>>>(adj, node_feat, part);
  k_dense1<<<512, 256, 0, stream>>>(node_feat, part, adj, W_g1, b_g1, h1, rsinv);
  // layer 2 (+ Aib/Bmat head precompute fused)
  k_adjgemm<<<512, 256, 0, stream>>>(adj, h1, part);
  k_dense2ab<<<512, 256, 0, stream>>>(h1, part, rsinv, W_g2, b_g2, W_c1, b_c1, Aib, Bmat);
  // fused edge stage: 1024 blocks x 4 waves; wave = 16 j x 16 i
  k_edge<<<1024, 256, 0, stream>>>(edge_feat, W_c1, W_c2, b_c2, Aib, Bmat, out);
}

// Round 11
// 125.612 us; speedup vs baseline: 1.2918x; 1.0176x over previous
//
#include <hip/hip_runtime.h>
#include <hip/hip_bf16.h>
#include <stdint.h>

constexpr int NN = 1024;   // nodes
constexpr int DD = 128;    // NODE_DIM == HID
constexpr int EDIM = 32;   // EDGE_DIM
constexpr int NR = 16;     // NREL

using short4v = __attribute__((ext_vector_type(4))) short;
using short8v = __attribute__((ext_vector_type(8))) short;
using f32x4   = __attribute__((ext_vector_type(4))) float;

__device__ __forceinline__ short f2bf(float x) {
  __hip_bfloat16 h = __float2bfloat16(x);   // RNE
  return __builtin_bit_cast(short, h);
}

__device__ __forceinline__ void nt_store4(float* p, const float4& v) {
  f32x4 t;
  t[0] = v.x; t[1] = v.y; t[2] = v.z; t[3] = v.w;
  __builtin_nontemporal_store(t, (f32x4*)p);
}

// ---------------- K2a v2: partial[kc][i][h] (float4-over-h, b32 adj broadcast) ----
__global__ __launch_bounds__(256) void k_adjgemm(const float* __restrict__ adj,
                                                 const float* __restrict__ X,
                                                 float* __restrict__ part) {
  __shared__ float sadj[16][136];          // pad 136: conflict-free broadcast reads
  int t = threadIdx.x;
  int ic = blockIdx.x & 63, kc = blockIdx.x >> 6;
  int i0 = ic * 16, k0 = kc * 128;
  {
    int il = t >> 4;
    int kl = (t & 15) * 8;
    const float4* src = (const float4*)(adj + (size_t)(i0 + il) * NN + k0 + kl);
    *(float4*)&sadj[il][kl]     = src[0];
    *(float4*)&sadj[il][kl + 4] = src[1];
  }
  __syncthreads();
  int hq = (t & 31) * 4;                   // h quad
  int ir = t >> 5;                         // 0..7
  float4 acc0 = {0,0,0,0}, acc1 = {0,0,0,0};
  const float* Xb = X + (size_t)k0 * DD + hq;
  #pragma unroll 4
  for (int k = 0; k < 128; ++k) {
    float4 xv = *(const float4*)(Xb + (size_t)k * DD);
    float a0 = sadj[ir][k];
    float a1 = sadj[ir + 8][k];
    acc0.x += a0 * xv.x; acc0.y += a0 * xv.y; acc0.z += a0 * xv.z; acc0.w += a0 * xv.w;
    acc1.x += a1 * xv.x; acc1.y += a1 * xv.y; acc1.z += a1 * xv.z; acc1.w += a1 * xv.w;
  }
  *(float4*)(part + ((size_t)kc * NN + (i0 + ir)) * DD + hq)     = acc0;
  *(float4*)(part + ((size_t)kc * NN + (i0 + ir + 8)) * DD + hq) = acc1;
}

// ---------------- K_dense1: rowsum + aggfin + dense layer1 ----------------
__global__ __launch_bounds__(256) void k_dense1(const float* __restrict__ X,
                                                const float* __restrict__ part,
                                                const float* __restrict__ adj,
                                                const float* __restrict__ W,
                                                const float* __restrict__ b,
                                                float* __restrict__ out,
                                                float* __restrict__ rsinv) {
  __shared__ float sagg[2][128];
  __shared__ float red[4];
  int t = threadIdx.x;
  int ig = t >> 7, h = t & 127;
  int i = blockIdx.x * 2 + ig;
  {   // rowsum(adj[i]) : 128 threads x 8 floats (adj is L2-hot from k_adjgemm)
    const float4* ar = (const float4*)(adj + (size_t)i * NN);
    float4 v0 = ar[h * 2], v1 = ar[h * 2 + 1];
    float s = v0.x + v0.y + v0.z + v0.w + v1.x + v1.y + v1.z + v1.w;
    #pragma unroll
    for (int off = 32; off > 0; off >>= 1) s += __shfl_down(s, off, 64);
    if ((t & 63) == 0) red[t >> 6] = s;
  }
  __syncthreads();
  float rs = 1.0f / (red[ig * 2] + red[ig * 2 + 1] + 1e-6f);
  if (h == 0) rsinv[i] = rs;
  {
    float ss = 0.f;
    #pragma unroll
    for (int kc = 0; kc < 8; ++kc) ss += part[(size_t)kc * NN * DD + (size_t)i * DD + h];
    sagg[ig][h] = ss * rs;
  }
  __syncthreads();
  const float4* xr = (const float4*)(X + (size_t)i * DD);
  const float4* ar = (const float4*)(&sagg[ig][0]);
  const float4* w1 = (const float4*)(W + (size_t)h * 256);
  const float4* w2 = (const float4*)(W + (size_t)h * 256 + DD);
  float acc = b[h];
  #pragma unroll 8
  for (int k = 0; k < 32; ++k) {
    float4 x = xr[k], w = w1[k];
    acc += x.x * w.x + x.y * w.y + x.z * w.z + x.w * w.w;
  }
  #pragma unroll 8
  for (int k = 0; k < 32; ++k) {
    float4 y = ar[k], w = w2[k];
    acc += y.x * w.x + y.y * w.y + y.z * w.z + y.w * w.w;
  }
  out[(size_t)i * DD + h] = fmaxf(acc, 0.f);
}

// ---------------- K_dense2ab: aggfin + dense layer2 + Aib/Bmat, fused ----------------
__global__ __launch_bounds__(256) void k_dense2ab(const float* __restrict__ X,
                                                  const float* __restrict__ part,
                                                  const float* __restrict__ rsinv,
                                                  const float* __restrict__ W,
                                                  const float* __restrict__ b,
                                                  const float* __restrict__ Wc1,
                                                  const float* __restrict__ bc1,
                                                  float* __restrict__ Aib,
                                                  float* __restrict__ Bmat) {
  __shared__ float sagg[2][128];
  __shared__ float sh2[2][128];
  int t = threadIdx.x;
  int ig = t >> 7, h = t & 127;
  int i = blockIdx.x * 2 + ig;
  {
    float ss = 0.f;
    #pragma unroll
    for (int kc = 0; kc < 8; ++kc) ss += part[(size_t)kc * NN * DD + (size_t)i * DD + h];
    sagg[ig][h] = ss * rsinv[i];
  }
  __syncthreads();
  {
    const float4* xr = (const float4*)(X + (size_t)i * DD);
    const float4* ar = (const float4*)(&sagg[ig][0]);
    const float4* w1 = (const float4*)(W + (size_t)h * 256);
    const float4* w2 = (const float4*)(W + (size_t)h * 256 + DD);
    float acc = b[h];
    #pragma unroll 8
    for (int k = 0; k < 32; ++k) {
      float4 x = xr[k], w = w1[k];
      acc += x.x * w.x + x.y * w.y + x.z * w.z + x.w * w.w;
    }
    #pragma unroll 8
    for (int k = 0; k < 32; ++k) {
      float4 y = ar[k], w = w2[k];
      acc += y.x * w.x + y.y * w.y + y.z * w.z + y.w * w.w;
    }
    sh2[ig][h] = fmaxf(acc, 0.f);
  }
  __syncthreads();
  // Aib/Bmat from the in-LDS h2 row
  const float4* xr = (const float4*)(&sh2[ig][0]);
  const float4* wa = (const float4*)(Wc1 + (size_t)h * 288);
  const float4* wb = (const float4*)(Wc1 + (size_t)h * 288 + 128);
  float aa = bc1[h], bb = 0.f;
  #pragma unroll 8
  for (int k = 0; k < 32; ++k) {
    float4 x = xr[k];
    float4 a = wa[k], b2 = wb[k];
    aa += x.x * a.x + x.y * a.y + x.z * a.z + x.w * a.w;
    bb += x.x * b2.x + x.y * b2.y + x.z * b2.z + x.w * b2.w;
  }
  Aib[(size_t)i * DD + h] = aa;
  Bmat[(size_t)i * DD + h] = bb;
}

// ---------------- K7: fused edge stage (v10: 6-deep rotating VGPR edge pipeline) ---
// Block: 16 i x 64 j; wave w: j = jg*64 + w*16 + c, bodies T=0..15 -> i0+T.
// Edge read directly to registers, rotation depth 6 (12 global_load_dwordx4 in
// flight per wave = 12 KB; 8 waves/CU = 96 KB/CU). No glds, no inline asm —
// the compiler emits exact waitcnts. Deferred GEMM2 + dbuf P + batch-4 nt flush.

#define EDGE_BODY(T, S, PF) do {                                              \
    float4 a_ = eA##S, b_ = eB##S;                                            \
    if (PF) {                                                                 \
      const float* p_ = ebl + (size_t)((T) + 6) * ((size_t)NN * EDIM);        \
      eA##S = *(const float4*)p_;                                             \
      eB##S = *(const float4*)(p_ + 4);                                       \
    }                                                                         \
    short8v ef_;                                                              \
    ef_[0]=f2bf(a_.x); ef_[1]=f2bf(a_.y); ef_[2]=f2bf(a_.z); ef_[3]=f2bf(a_.w); \
    ef_[4]=f2bf(b_.x); ef_[5]=f2bf(b_.y); ef_[6]=f2bf(b_.z); ef_[7]=f2bf(b_.w); \
    char* pw_ = psm + (((T) & 1) << 12);                                      \
    const float* ap_ = aibs + (T) * 128 + 4 * g;                              \
    _Pragma("unroll")                                                         \
    for (int n = 0; n < 8; ++n) {                                             \
      float4 av_ = *(const float4*)(ap_ + 16 * n);                            \
      f32x4 ci_;                                                              \
      ci_[0] = av_.x + bjv[n].x; ci_[1] = av_.y + bjv[n].y;                   \
      ci_[2] = av_.z + bjv[n].z; ci_[3] = av_.w + bjv[n].w;                   \
      f32x4 acc_ = __builtin_amdgcn_mfma_f32_16x16x32_bf16(weF[n], ef_, ci_, 0, 0, 0); \
      short4v pk_;                                                            \
      pk_[0] = f2bf(fmaxf(acc_[0], 0.f)); pk_[1] = f2bf(fmaxf(acc_[1], 0.f)); \
      pk_[2] = f2bf(fmaxf(acc_[2], 0.f)); pk_[3] = f2bf(fmaxf(acc_[3], 0.f)); \
      *(short4v*)(pw_ + (((n >> 1) << 10) + ((n & 1) << 9) + wroff)) = pk_;   \
    }                                                                         \
  } while (0)

#define G2(G2T, OREG) do {                                                    \
    f32x4 a2_;                                                                \
    a2_[0] = bc2v.x; a2_[1] = bc2v.y; a2_[2] = bc2v.z; a2_[3] = bc2v.w;       \
    const char* pp_ = psm + (((G2T) & 1) << 12);                              \
    _Pragma("unroll")                                                         \
    for (int kk = 0; kk < 4; ++kk) {                                          \
      short8v pb_ = *(const short8v*)(pp_ + ((kk << 10) + rdP));              \
      a2_ = __builtin_amdgcn_mfma_f32_16x16x32_bf16(wcF[kk], pb_, a2_, 0, 0, 0); \
    }                                                                         \
    bool dg_ = (j == i0 + (G2T));                                             \
    OREG.x = dg_ ? 0.f : a2_[0];                                              \
    OREG.y = dg_ ? 0.f : a2_[1];                                              \
    OREG.z = dg_ ? 0.f : a2_[2];                                              \
    OREG.w = dg_ ? 0.f : a2_[3];                                              \
  } while (0)

#define FLUSH(BASE) do {                                                      \
    nt_store4(out + ((size_t)(i0 + (BASE) + 0) * NN + j) * NR + 4 * g, o0);   \
    nt_store4(out + ((size_t)(i0 + (BASE) + 1) * NN + j) * NR + 4 * g, o1);   \
    nt_store4(out + ((size_t)(i0 + (BASE) + 2) * NN + j) * NR + 4 * g, o2);   \
    nt_store4(out + ((size_t)(i0 + (BASE) + 3) * NN + j) * NR + 4 * g, o3);   \
  } while (0)

__global__ __launch_bounds__(256, 2) void k_edge(const float* __restrict__ edge,
                                                 const float* __restrict__ Wc1,
                                                 const float* __restrict__ Wc2,
                                                 const float* __restrict__ bc2,
                                                 const float* __restrict__ Aib,
                                                 const float* __restrict__ Bmat,
                                                 float* __restrict__ out) {
  __shared__ __align__(16) char psm_all[4][2][4096]; // 32 KB P tiles (dbuf per wave)
  __shared__ __align__(16) float aibs[16 * 128];     // 8 KB Aib panel -> 40 KB total
  int tid = threadIdx.x;
  int w = tid >> 6, lane = tid & 63;
  int c = lane & 15, g = lane >> 4;
  int ig = blockIdx.x >> 4, jg = blockIdx.x & 15;
  int i0 = ig * 16;
  int j0w = jg * 64 + w * 16;
  int j = j0w + c;

  // stage Aib panel (16 i x 128 h) into LDS
  {
    int ii = tid >> 4, h8 = (tid & 15) * 8;
    const float4* s = (const float4*)(Aib + (size_t)(i0 + ii) * DD + h8);
    *(float4*)(aibs + ii * 128 + h8)     = s[0];
    *(float4*)(aibs + ii * 128 + h8 + 4) = s[1];
  }

  // We fragments: A1[m=c][k=8g+jj] = Wc1[16n+c][256+8g+jj]
  short8v weF[8];
  #pragma unroll
  for (int n = 0; n < 8; ++n) {
    const float* p = Wc1 + (size_t)(16 * n + c) * 288 + 256 + 8 * g;
    float4 f0 = *(const float4*)p;
    float4 f1 = *(const float4*)(p + 4);
    short8v s;
    s[0]=f2bf(f0.x); s[1]=f2bf(f0.y); s[2]=f2bf(f0.z); s[3]=f2bf(f0.w);
    s[4]=f2bf(f1.x); s[5]=f2bf(f1.y); s[6]=f2bf(f1.z); s[7]=f2bf(f1.w);
    weF[n] = s;
  }
  // Wc2 fragments: A2[m=c][k=32kk+8g+jj]
  short8v wcF[4];
  #pragma unroll
  for (int kk = 0; kk < 4; ++kk) {
    const float* p = Wc2 + (size_t)c * DD + 32 * kk + 8 * g;
    float4 f0 = *(const float4*)p;
    float4 f1 = *(const float4*)(p + 4);
    short8v s;
    s[0]=f2bf(f0.x); s[1]=f2bf(f0.y); s[2]=f2bf(f0.z); s[3]=f2bf(f0.w);
    s[4]=f2bf(f1.x); s[5]=f2bf(f1.y); s[6]=f2bf(f1.z); s[7]=f2bf(f1.w);
    wcF[kk] = s;
  }
  float4 bc2v = *(const float4*)(bc2 + 4 * g);
  // Bmat for this lane's j, reused across all 16 i's
  float4 bjv[8];
  #pragma unroll
  for (int n = 0; n < 8; ++n)
    bjv[n] = *(const float4*)(Bmat + (size_t)j * DD + 16 * n + 4 * g);

  __syncthreads();   // aibs ready

  char* psm = &psm_all[w][0][0];
  // per-lane edge base: lane (c,g) covers (j, dims 8g..8g+7); advance 128KB per i
  const float* ebl = edge + ((size_t)i0 * NN + j) * EDIM + 8 * g;
  // P-tile write/read offsets (derived conflict-free transpose layout)
  int wroff = (c << 4) + ((g & 1) << 3) + ((g >> 1) << 8);
  int rdP   = (g << 8) + (c << 4);

  float4 o0, o1, o2, o3;

  // prologue: fill rotation slots 0..5 with bodies 0..5 (12 loads in flight)
  float4 eA0, eB0, eA1, eB1, eA2, eB2, eA3, eB3, eA4, eB4, eA5, eB5;
  {
    const size_t STP = (size_t)NN * EDIM;
    eA0 = *(const float4*)(ebl);            eB0 = *(const float4*)(ebl + 4);
    eA1 = *(const float4*)(ebl + STP);      eB1 = *(const float4*)(ebl + STP + 4);
    eA2 = *(const float4*)(ebl + 2 * STP);  eB2 = *(const float4*)(ebl + 2 * STP + 4);
    eA3 = *(const float4*)(ebl + 3 * STP);  eB3 = *(const float4*)(ebl + 3 * STP + 4);
    eA4 = *(const float4*)(ebl + 4 * STP);  eB4 = *(const float4*)(ebl + 4 * STP + 4);
    eA5 = *(const float4*)(ebl + 5 * STP);  eB5 = *(const float4*)(ebl + 5 * STP + 4);
  }

  EDGE_BODY(0, 0, 1);
  EDGE_BODY(1, 1, 1);  G2(0, o0);
  EDGE_BODY(2, 2, 1);  G2(1, o1);
  EDGE_BODY(3, 3, 1);  G2(2, o2);
  EDGE_BODY(4, 4, 1);  G2(3, o3);  FLUSH(0);
  EDGE_BODY(5, 5, 1);  G2(4, o0);
  EDGE_BODY(6, 0, 1);  G2(5, o1);
  EDGE_BODY(7, 1, 1);  G2(6, o2);
  EDGE_BODY(8, 2, 1);  G2(7, o3);  FLUSH(4);
  EDGE_BODY(9, 3, 1);  G2(8, o0);
  EDGE_BODY(10, 4, 0); G2(9, o1);
  EDGE_BODY(11, 5, 0); G2(10, o2);
  EDGE_BODY(12, 0, 0); G2(11, o3); FLUSH(8);
  EDGE_BODY(13, 1, 0); G2(12, o0);
  EDGE_BODY(14, 2, 0); G2(13, o1);
  EDGE_BODY(15, 3, 0); G2(14, o2);
  G2(15, o3); FLUSH(12);
}

extern "C" void kernel_launch(void* const* d_in, const int* in_sizes, int n_in,
                              void* d_out, int out_size, void* d_ws, size_t ws_size,
                              hipStream_t stream) {
  const float* node_feat = (const float*)d_in[0];
  const float* edge_feat = (const float*)d_in[1];
  const float* adj  = (const float*)d_in[2];
  const float* W_g1 = (const float*)d_in[3];
  const float* b_g1 = (const float*)d_in[4];
  const float* W_g2 = (const float*)d_in[5];
  const float* b_g2 = (const float*)d_in[6];
  const float* W_c1 = (const float*)d_in[7];
  const float* b_c1 = (const float*)d_in[8];
  const float* W_c2 = (const float*)d_in[9];
  const float* b_c2 = (const float*)d_in[10];
  float* out = (float*)d_out;

  float* ws    = (float*)d_ws;
  float* rsinv = ws;                        // 1024
  float* part  = ws + 1024;                 // 8*1024*128
  float* h1    = part + 8 * NN * DD;        // 131072
  float* Aib   = h1 + NN * DD;              // 131072
  float* Bmat  = Aib + NN * DD;             // 131072

  // layer 1 (rowsum fused into dense1)
  k_adjgemm<<<512, 256, 0, stream>>>(adj, node_feat, part);
  k_dense1<<<512, 256, 0, stream>>>(node_feat, part, adj, W_g1, b_g1, h1, rsinv);
  // layer 2 (+ Aib/Bmat head precompute fused)
  k_adjgemm<<<512, 256, 0, stream>>>(adj, h1, part);
  k_dense2ab<<<512, 256, 0, stream>>>(h1, part, rsinv, W_g2, b_g2, W_c1, b_c1, Aib, Bmat);
  // fused edge stage: 1024 blocks x 4 waves; wave = 16 j x 16 i
  k_edge<<<1024, 256, 0, stream>>>(edge_feat, W_c1, W_c2, b_c2, Aib, Bmat, out);
}